// Round 16
// baseline (3752.096 us; speedup 1.0000x reference)
//
#include <hip/hip_runtime.h>
#include <hip/hip_bf16.h>

using bf16x8 = __attribute__((ext_vector_type(8))) __bf16;
using short8 = __attribute__((ext_vector_type(8))) short;
using f32x4  = __attribute__((ext_vector_type(4))) float;
using f4     = __attribute__((ext_vector_type(4))) float;
using i32x4  = __attribute__((ext_vector_type(4))) int;

constexpr int NB = 128;    // batch
constexpr int NT = 256;    // time
constexpr int NH = 1024;   // hidden
constexpr int NE = 256;    // embed
constexpr int NV = 256;    // vocab

constexpr int WHH_BYTES = 48 * 2048;    // 98304: 48 rows x 1024 bf16
// sGh tiles: 30 tiles of 16 rows x 16 cols, ROW STRIDE 18 floats (tile=288).
// Old stride 16: the four 16-lane groups hit the same 16 banks (64 = 0 mod
// 32) -> uniform 4-way conflict on every partial write/read (6.6e7/dispatch).
// Stride 18: group stride 72 = 8 mod 32 -> spread over 32 banks, 2-way (free).
constexpr int TS = 288;                 // floats per tile
constexpr int GH_FLOATS = 30 * TS;      // 8640 floats
constexpr int NBLK = 256;

// ---- cache-bypass (coherence-point) memory ops ----
__device__ __forceinline__ void ldg_sc(i32x4& d, const void* p) {
  asm volatile("global_load_dwordx4 %0, %1, off sc0 sc1" : "=v"(d) : "v"(p));
}
__device__ __forceinline__ void ldg_c(i32x4& d, const void* p) {
  asm volatile("global_load_dwordx4 %0, %1, off" : "=v"(d) : "v"(p));
}
__device__ __forceinline__ void stg_sc(void* p, i32x4 v) {
  asm volatile("global_store_dwordx4 %0, %1, off sc0 sc1" :: "v"(p), "v"(v) : "memory");
}
__device__ __forceinline__ void vm0_fence() {
  asm volatile("s_waitcnt vmcnt(0)" ::: "memory");
}
__device__ __forceinline__ void use_dep(i32x4& d) {
  asm volatile("" : "+v"(d));
}

// 8 contiguous f32 -> bf16x8 (RNE)
__device__ __forceinline__ bf16x8 cvt8(const float* p) {
  short8 r;
  #pragma unroll
  for (int j = 0; j < 8; ++j)
    r[j] = (short)__bfloat16_as_ushort(__float2bfloat16(p[j]));
  return __builtin_bit_cast(bf16x8, r);
}

__global__ __launch_bounds__(256) void embcvt_kernel(const float* __restrict__ e,
                                                     __hip_bfloat16* __restrict__ o) {
  int i = blockIdx.x * 256 + threadIdx.x;
  o[i] = __float2bfloat16(e[i]);
}

// 256 WGs x 384 threads. WG owns h'[rb*32:+32, c0:+16]. Wave wv=(mt,ks):
// hh GEMM = m-tile mt, K-slice ks, all 3 gates; input GEMM = gate ks,
// K-HALF mt. Both layers prefetch input fragments one step ahead; the
// step-top input GEMM is pure register compute with partials pre-poll.
template<int LAYER>
__device__ __forceinline__ void gru_body(
    const int* __restrict__ x,
    const __hip_bfloat16* __restrict__ embb,
    const float* __restrict__ Wih,
    const float* __restrict__ Whh,
    const float* __restrict__ bih,
    const float* __restrict__ bhh,
    const float* __restrict__ h0,
    const __hip_bfloat16* __restrict__ yin,   // [T][B][H] (layer1 input)
    __hip_bfloat16* __restrict__ yout,        // [T][B][H] (layer0 output)
    __hip_bfloat16* __restrict__ hbuf,        // [2][128][1024]
    float* __restrict__ hout,
    unsigned int* __restrict__ flags)         // [4][64][16] uints
{
  extern __shared__ char smem[];
  char*  sWhh  = smem;
  float* sGh   = (float*)(smem + WHH_BYTES);
  float* sBias = sGh + GH_FLOATS;
  char*  sH    = (char*)(sBias + 64);         // 32x16 bf16 h' staging (1KB)

  const int tid  = threadIdx.x;
  const int lane = tid & 63;
  const int wv   = tid >> 6;
  const int mt   = wv & 1;
  const int ks   = wv >> 1;                   // K-slice / input gate, 0..2
  const int b    = blockIdx.x;
  const int rb   = (b >> 1) & 3;
  const int cidx = (b & 1) * 32 + (b >> 3);
  const int r0   = rb * 32;
  const int c0   = cidx * 16;
  unsigned int* pf = flags + rb * 64 * 16;
  const int slot = cidx;
  const int l16  = lane & 15;
  const int lk8  = (lane >> 4) * 8;

  // ---- stage W_hh slice swizzled (rows gate-major: gr>>4 = gate) ----
  for (int it = 0; it < 16; ++it) {
    int idx = it * 384 + tid;
    int gr = idx >> 7, kc = idx & 127;
    int grow = (gr >> 4) * NH + c0 + (gr & 15);
    short8 v = __builtin_bit_cast(short8, cvt8(Whh + grow * NH + kc * 8));
    *(short8*)(sWhh + ((gr * 2048 + kc * 16) ^ ((gr & 7) << 4))) = v;
  }
  if (tid < 16)       sBias[tid] = bih[c0 + tid] + bhh[c0 + tid];
  else if (tid < 32)  { int c = NH + c0 + tid - 16;   sBias[tid] = bih[c] + bhh[c]; }
  else if (tid < 48)  { int c = 2*NH + c0 + tid - 32; sBias[tid] = bih[c]; }
  else if (tid < 64)  { int c = 2*NH + c0 + tid - 48; sBias[tid] = bhh[c]; }

  // ---- W_ih VGPR fragments: gate ks, K-half mt (no spill) ----
  constexpr int KIN   = (LAYER == 0) ? NE : NH;
  constexpr int NFRAG = KIN / 64;             // L0: 4, L1: 16
  const int khalf = mt * (KIN / 2);
  bf16x8 wreg[NFRAG];
  #pragma unroll
  for (int kf = 0; kf < NFRAG; ++kf) {
    int grow = ks * NH + c0 + l16;
    wreg[kf] = cvt8(Wih + grow * KIN + khalf + kf * 32 + lk8);
  }

  // ---- init h0 -> regs + sH -> staged sc publish + flag=1 ----
  float hown[2] = {0.f, 0.f};
  #pragma unroll
  for (int ei = 0; ei < 2; ++ei) {
    int e = tid + ei * 384;
    if (e < 512) {
      float hv = h0[(r0 + (e >> 4)) * NH + c0 + (e & 15)];
      hown[ei] = hv;
      ((unsigned short*)sH)[e] = __bfloat16_as_ushort(__float2bfloat16(hv));
    }
  }
  __syncthreads();
  if (tid < 64) {
    i32x4 hv = *(const i32x4*)(sH + (tid >> 1) * 32 + (tid & 1) * 16);
    stg_sc(hbuf + (r0 + (tid >> 1)) * NH + c0 + (tid & 1) * 8, hv);
    vm0_fence();
    if (tid == 0)
      __hip_atomic_store(pf + slot * 16, 1u, __ATOMIC_RELAXED,
                         __HIP_MEMORY_SCOPE_AGENT);
  }

  // ---- prologue prefetch of step-0 input fragments ----
  i32x4 pe0[(LAYER == 0) ? 4 : 16];
  i32x4 pe1[(LAYER == 0) ? 4 : 1];
  int xq0 = 0, xq1 = 0;
  if constexpr (LAYER == 0) {
    xq0 = x[(r0 + l16) * NT + 0];
    xq1 = x[(r0 + 16 + l16) * NT + 0];
    const __hip_bfloat16* e0 = embb + xq0 * NE + khalf + lk8;
    const __hip_bfloat16* e1 = embb + xq1 * NE + khalf + lk8;
    #pragma unroll
    for (int kf = 0; kf < 4; ++kf) { ldg_c(pe0[kf], e0 + kf * 32); ldg_c(pe1[kf], e1 + kf * 32); }
    vm0_fence();
    #pragma unroll
    for (int kf = 0; kf < 4; ++kf) { use_dep(pe0[kf]); use_dep(pe1[kf]); }
  } else {
    const __hip_bfloat16* yp = yin + ((size_t)0 * NB + (r0 + l16)) * NH + khalf + lk8;
    #pragma unroll
    for (int kf = 0; kf < 16; ++kf) ldg_c(pe0[kf], yp + kf * 32);
    vm0_fence();
    #pragma unroll
    for (int kf = 0; kf < 16; ++kf) use_dep(pe0[kf]);
  }

  // ---- time loop ----
  for (int t = 0; t < NT; ++t) {
    const __hip_bfloat16* rbuf = hbuf + (t & 1) * (NB * NH);
    __hip_bfloat16* wbuf = hbuf + ((t + 1) & 1) * (NB * NH);
    const int arow = r0 + mt * 16 + l16;
    const int bxor = (l16 & 7) << 4;
    float* abase = sGh + (lane >> 4) * 72 + l16;   // row=(lane>>4)*4+j -> +j*18

    // ---- 1. input GEMM from prefetched regs (pure reg compute, PRE-POLL) ----
    f32x4 ai0 = {0.f,0.f,0.f,0.f}, ai1 = {0.f,0.f,0.f,0.f};
    vm0_fence();
    if constexpr (LAYER == 0) {
      #pragma unroll
      for (int kf = 0; kf < 4; ++kf) { use_dep(pe0[kf]); use_dep(pe1[kf]); }
      #pragma unroll
      for (int kf = 0; kf < 4; ++kf) {
        ai0 = __builtin_amdgcn_mfma_f32_16x16x32_bf16(
            __builtin_bit_cast(bf16x8, pe0[kf]), wreg[kf], ai0, 0, 0, 0);
        ai1 = __builtin_amdgcn_mfma_f32_16x16x32_bf16(
            __builtin_bit_cast(bf16x8, pe1[kf]), wreg[kf], ai1, 0, 0, 0);
      }
      float* pi0 = abase + (18 + (ks * 2 + mt) * 2 + 0) * TS;
      float* pi1 = abase + (18 + (ks * 2 + mt) * 2 + 1) * TS;
      pi0[0]=ai0[0]; pi0[18]=ai0[1]; pi0[36]=ai0[2]; pi0[54]=ai0[3];
      pi1[0]=ai1[0]; pi1[18]=ai1[1]; pi1[36]=ai1[2]; pi1[54]=ai1[3];
    } else {
      #pragma unroll
      for (int kf = 0; kf < 16; ++kf) use_dep(pe0[kf]);
      #pragma unroll
      for (int kf = 0; kf < 16; ++kf) {
        ai0 = __builtin_amdgcn_mfma_f32_16x16x32_bf16(
            __builtin_bit_cast(bf16x8, pe0[kf]), wreg[kf], ai0, 0, 0, 0);
      }
    }

    // ---- 2. wait for all producers of h(t) (wave0 polls padded flags) ----
    {
      unsigned int ep = (unsigned int)(t + 1);
      if (tid < 64) {
        const unsigned int* f = pf + tid * 16;
        while (__hip_atomic_load(f, __ATOMIC_RELAXED,
                                 __HIP_MEMORY_SCOPE_AGENT) < ep)
          __builtin_amdgcn_s_sleep(1);
      }
      __syncthreads();
    }

    // ---- 3a. issue ALL A sc-loads; L0 also next-step x ids (shadowed) ----
    const int nk = (ks < 2) ? 11 : 10;
    const __hip_bfloat16* aptr = rbuf + arow * NH + lk8;
    i32x4 fr[11];
    #pragma unroll
    for (int i = 0; i < 11; ++i)
      if (i < nk) ldg_sc(fr[i], aptr + (ks + 3 * i) * 32);
    if constexpr (LAYER == 0) {
      int tn = (t + 1 < NT) ? (t + 1) : (NT - 1);
      xq0 = x[(r0 + l16) * NT + tn];
      xq1 = x[(r0 + 16 + l16) * NT + tn];
    }

    // ---- 1b. (L1 only) input GEMM m-tile 1 (hides A-load round trip) ----
    if constexpr (LAYER == 1) {
      const __hip_bfloat16* xp1 = yin + ((size_t)t * NB + (r0 + 16 + l16)) * NH + khalf + lk8;
      #pragma unroll
      for (int kf = 0; kf < 16; ++kf) {
        bf16x8 a = __builtin_bit_cast(bf16x8, *(const short8*)(xp1 + kf * 32));
        ai1 = __builtin_amdgcn_mfma_f32_16x16x32_bf16(a, wreg[kf], ai1, 0, 0, 0);
      }
      float* pi0 = abase + (18 + (ks * 2 + mt) * 2 + 0) * TS;
      float* pi1 = abase + (18 + (ks * 2 + mt) * 2 + 1) * TS;
      pi0[0]=ai0[0]; pi0[18]=ai0[1]; pi0[36]=ai0[2]; pi0[54]=ai0[3];
      pi1[0]=ai1[0]; pi1[18]=ai1[1]; pi1[36]=ai1[2]; pi1[54]=ai1[3];
    }

    // ---- 3b. W_hh MFMAs: A from regs, all 3 gates per chunk ----
    vm0_fence();
    #pragma unroll
    for (int i = 0; i < 11; ++i)
      if (i < nk) use_dep(fr[i]);
    {
      f32x4 ah0 = {0.f,0.f,0.f,0.f}, ah1 = {0.f,0.f,0.f,0.f}, ah2 = {0.f,0.f,0.f,0.f};
      const int bb0 = (l16)      * 2048 + lk8 * 2;
      const int bb1 = (16 + l16) * 2048 + lk8 * 2;
      const int bb2 = (32 + l16) * 2048 + lk8 * 2;
      #pragma unroll
      for (int i = 0; i < 11; ++i) {
        if (i < nk) {
          int kk = ks + 3 * i;
          bf16x8 a = __builtin_bit_cast(bf16x8, fr[i]);
          bf16x8 b0 = __builtin_bit_cast(bf16x8,
              *(const short8*)(sWhh + ((bb0 + kk * 64) ^ bxor)));
          ah0 = __builtin_amdgcn_mfma_f32_16x16x32_bf16(a, b0, ah0, 0, 0, 0);
          bf16x8 b1 = __builtin_bit_cast(bf16x8,
              *(const short8*)(sWhh + ((bb1 + kk * 64) ^ bxor)));
          ah1 = __builtin_amdgcn_mfma_f32_16x16x32_bf16(a, b1, ah1, 0, 0, 0);
          bf16x8 b2 = __builtin_bit_cast(bf16x8,
              *(const short8*)(sWhh + ((bb2 + kk * 64) ^ bxor)));
          ah2 = __builtin_amdgcn_mfma_f32_16x16x32_bf16(a, b2, ah2, 0, 0, 0);
        }
      }
      float* p0 = abase + (ks * 6 + mt * 3 + 0) * TS;
      float* p1 = abase + (ks * 6 + mt * 3 + 1) * TS;
      float* p2 = abase + (ks * 6 + mt * 3 + 2) * TS;
      p0[0]=ah0[0]; p0[18]=ah0[1]; p0[36]=ah0[2]; p0[54]=ah0[3];
      p1[0]=ah1[0]; p1[18]=ah1[1]; p1[36]=ah1[2]; p1[54]=ah1[3];
      p2[0]=ah2[0]; p2[18]=ah2[1]; p2[36]=ah2[2]; p2[54]=ah2[3];
    }
    __syncthreads();

    // ---- 4. gates: sum partials; h' -> sH only ----
    #pragma unroll
    for (int ei = 0; ei < 2; ++ei) {
      int e = tid + ei * 384;
      if (e < 512) {
        int lrow = e >> 4, lcol = e & 15;
        int m2 = lrow >> 4, off = (lrow & 15) * 18 + lcol;
        float ghr = sGh[(0*6 + m2*3 + 0) * TS + off]
                  + sGh[(1*6 + m2*3 + 0) * TS + off]
                  + sGh[(2*6 + m2*3 + 0) * TS + off];
        float ghz = sGh[(0*6 + m2*3 + 1) * TS + off]
                  + sGh[(1*6 + m2*3 + 1) * TS + off]
                  + sGh[(2*6 + m2*3 + 1) * TS + off];
        float ghn = sGh[(0*6 + m2*3 + 2) * TS + off]
                  + sGh[(1*6 + m2*3 + 2) * TS + off]
                  + sGh[(2*6 + m2*3 + 2) * TS + off];
        float gir = sGh[(18 + (0*2+0)*2 + m2) * TS + off]
                  + sGh[(18 + (0*2+1)*2 + m2) * TS + off];
        float giz = sGh[(18 + (1*2+0)*2 + m2) * TS + off]
                  + sGh[(18 + (1*2+1)*2 + m2) * TS + off];
        float gin = sGh[(18 + (2*2+0)*2 + m2) * TS + off]
                  + sGh[(18 + (2*2+1)*2 + m2) * TS + off];
        float r = 1.f / (1.f + __expf(-(gir + ghr + sBias[lcol])));
        float z = 1.f / (1.f + __expf(-(giz + ghz + sBias[16 + lcol])));
        float npre = (gin + sBias[32 + lcol]) + r * (ghn + sBias[48 + lcol]);
        float n = 2.f / (1.f + __expf(-2.f * npre)) - 1.f;   // tanh, inf-safe
        float hn = (1.f - z) * n + z * hown[ei];
        hown[ei] = hn;
        ((unsigned short*)sH)[e] = __bfloat16_as_ushort(__float2bfloat16(hn));
      }
    }

    // ---- 4b. prefetch next period's input fragments ----
    if constexpr (LAYER == 0) {
      const __hip_bfloat16* e0 = embb + xq0 * NE + khalf + lk8;
      const __hip_bfloat16* e1 = embb + xq1 * NE + khalf + lk8;
      #pragma unroll
      for (int kf = 0; kf < 4; ++kf) { ldg_c(pe0[kf], e0 + kf * 32); ldg_c(pe1[kf], e1 + kf * 32); }
    } else {
      int tn = (t + 1 < NT) ? (t + 1) : (NT - 1);
      const __hip_bfloat16* yp = yin + ((size_t)tn * NB + (r0 + l16)) * NH + khalf + lk8;
      #pragma unroll
      for (int kf = 0; kf < 16; ++kf) ldg_c(pe0[kf], yp + kf * 32);
    }

    // ---- 5. publish h' (wave0, sc) + flag; wave1 stores y0 (off-chain) ----
    __syncthreads();
    if constexpr (LAYER == 0) {
      if (tid >= 64 && tid < 128) {
        int l = tid & 63;
        i32x4 hv = *(const i32x4*)(sH + (l >> 1) * 32 + (l & 1) * 16);
        *(i32x4*)(yout + ((size_t)t * NB + (r0 + (l >> 1))) * NH + c0 + (l & 1) * 8) = hv;
      }
    }
    if (tid < 64) {
      i32x4 hv = *(const i32x4*)(sH + (tid >> 1) * 32 + (tid & 1) * 16);
      stg_sc(wbuf + (r0 + (tid >> 1)) * NH + c0 + (tid & 1) * 8, hv);
      vm0_fence();
      if (tid == 0)
        __hip_atomic_store(pf + slot * 16, (unsigned int)(t + 2),
                           __ATOMIC_RELAXED, __HIP_MEMORY_SCOPE_AGENT);
    }
  }

  #pragma unroll
  for (int ei = 0; ei < 2; ++ei) {
    int e = tid + ei * 384;
    if (e < 512) {
      int lrow = e >> 4, lcol = e & 15;
      hout[(r0 + lrow) * NH + c0 + lcol] = hown[ei];
    }
  }
}

// Distinct names so rocprof rows attribute the slow dispatch to a layer.
__global__ __launch_bounds__(384, 1) void gru0_kernel(
    const int* x, const __hip_bfloat16* embb, const float* Wih,
    const float* Whh, const float* bih, const float* bhh, const float* h0,
    const __hip_bfloat16* yin, __hip_bfloat16* yout, __hip_bfloat16* hbuf,
    float* hout, unsigned int* flags) {
  gru_body<0>(x, embb, Wih, Whh, bih, bhh, h0, yin, yout, hbuf, hout, flags);
}
__global__ __launch_bounds__(384, 1) void gru1_kernel(
    const int* x, const __hip_bfloat16* embb, const float* Wih,
    const float* Whh, const float* bih, const float* bhh, const float* h0,
    const __hip_bfloat16* yin, __hip_bfloat16* yout, __hip_bfloat16* hbuf,
    float* hout, unsigned int* flags) {
  gru_body<1>(x, embb, Wih, Whh, bih, bhh, h0, yin, yout, hbuf, hout, flags);
}

__global__ __launch_bounds__(256) void logits_kernel(
    const __hip_bfloat16* __restrict__ h1,
    const float* __restrict__ fcW,
    const float* __restrict__ fcb,
    float* __restrict__ out)
{
  __shared__ float hrow[NH];
  int b = blockIdx.x, v = threadIdx.x;
  if (v < 128) {
    i32x4 hv;
    ldg_sc(hv, h1 + b * NH + v * 8);
    vm0_fence();
    use_dep(hv);
    short8 s = __builtin_bit_cast(short8, hv);
    #pragma unroll
    for (int j = 0; j < 8; ++j) {
      union { unsigned int i; float f; } c;
      c.i = ((unsigned int)(unsigned short)s[j]) << 16;
      hrow[v * 8 + j] = c.f;
    }
  }
  __syncthreads();
  float acc = fcb[v];
  for (int k = 0; k < NH; k += 4) {
    f4 wv = *(const f4*)(fcW + v * NH + k);
    #pragma unroll
    for (int j = 0; j < 4; ++j) acc += wv[j] * hrow[k + j];
  }
  out[b * NV + v] = acc;
}

extern "C" void kernel_launch(void* const* d_in, const int* in_sizes, int n_in,
                              void* d_out, int out_size, void* d_ws, size_t ws_size,
                              hipStream_t stream) {
  const int*   x    = (const int*)d_in[0];
  const float* h0   = (const float*)d_in[1];
  const float* emb  = (const float*)d_in[2];
  const float* Wih0 = (const float*)d_in[3];
  const float* Whh0 = (const float*)d_in[4];
  const float* bih0 = (const float*)d_in[5];
  const float* bhh0 = (const float*)d_in[6];
  const float* Wih1 = (const float*)d_in[7];
  const float* Whh1 = (const float*)d_in[8];
  const float* bih1 = (const float*)d_in[9];
  const float* bhh1 = (const float*)d_in[10];
  const float* fcW  = (const float*)d_in[11];
  const float* fcb  = (const float*)d_in[12];
  float* out = (float*)d_out;

  char* ws = (char*)d_ws;
  size_t off = 0;
  __hip_bfloat16* y0   = (__hip_bfloat16*)ws;            off += (size_t)NB * NT * NH * 2;  // [T][B][H]
  __hip_bfloat16* hbuf = (__hip_bfloat16*)(ws + off);    off += (size_t)2 * NB * NH * 2;
  __hip_bfloat16* embb = (__hip_bfloat16*)(ws + off);    off += (size_t)NV * NE * 2;
  unsigned int*  flags0 = (unsigned int*)(ws + off);     off += 4 * 64 * 16 * 4;
  unsigned int*  flags1 = (unsigned int*)(ws + off);     off += 4 * 64 * 16 * 4;

  (void)hipMemsetAsync(flags0, 0, 2 * 4 * 64 * 16 * 4, stream);
  embcvt_kernel<<<dim3(NV * NE / 256), dim3(256), 0, stream>>>(emb, embb);

  constexpr int lds = WHH_BYTES + GH_FLOATS * 4 + 64 * 4 + 1024;  // 134144
  (void)hipFuncSetAttribute(reinterpret_cast<const void*>(gru0_kernel),
                            hipFuncAttributeMaxDynamicSharedMemorySize, lds);
  (void)hipFuncSetAttribute(reinterpret_cast<const void*>(gru1_kernel),
                            hipFuncAttributeMaxDynamicSharedMemorySize, lds);

  gru0_kernel<<<dim3(NBLK), dim3(384), lds, stream>>>(
      x, embb, Wih0, Whh0, bih0, bhh0, h0, y0, y0, hbuf, out + 32768, flags0);
  gru1_kernel<<<dim3(NBLK), dim3(384), lds, stream>>>(
      x, embb, Wih1, Whh1, bih1, bhh1, h0 + NB * NH, y0, y0, hbuf,
      out + 32768 + NB * NH, flags1);
  logits_kernel<<<dim3(NB), dim3(256), 0, stream>>>(hbuf, fcW, fcb, out);
}